// Round 4
// baseline (104.625 us; speedup 1.0000x reference)
//
#include <hip/hip_runtime.h>
#include <hip/hip_bf16.h>
#include <math.h>

// BlockSoftmaxLinearHybrid: B=2,H=16,L=4096,D=64,F=64,S=64
constexpr int Hc = 16, Lc = 4096, Dc = 64, Sc = 64;
constexpr int Nc = Lc / Sc;        // 64 tiles along L per (b,h)
constexpr int F2 = 128;
constexpr int BH = 32;
constexpr int CH = 4;              // tiles per chunk
constexpr int CPB = Nc / CH;       // 16 chunks per (b,h)
constexpr int NCHUNK = BH * CPB;   // 512 blocks
constexpr float EPSf = 1e-6f;
constexpr float SCALE = 0.125f;    // D^-0.5

typedef short short8 __attribute__((ext_vector_type(8)));     // 8 bf16 MFMA A/B frag
typedef float f32x4 __attribute__((ext_vector_type(4)));      // MFMA C/D frag
typedef unsigned short ushort;
typedef ushort ushort4v __attribute__((ext_vector_type(4)));

__device__ inline ushort f2bf(float x) {            // fp32 -> bf16 RNE
    unsigned u = __builtin_bit_cast(unsigned, x);
    u = (u + 0x7fffu + ((u >> 16) & 1u)) >> 16;
    return (ushort)u;
}
__device__ inline f32x4 zero4() { f32x4 z = {0.f, 0.f, 0.f, 0.f}; return z; }

__device__ inline f32x4 mfma(short8 a, short8 b, f32x4 c) {
    return __builtin_amdgcn_mfma_f32_16x16x32_bf16(a, b, c, 0, 0, 0);
}

// LDS fragment read, XOR-swizzled 16B chunks (T2)
__device__ inline short8 ldfrag(const char* L, int row, int chunk, int rowbytes, int mask) {
    return *(const short8*)(L + row * rowbytes + ((chunk * 16) ^ ((row & mask) << 4)));
}

// Direct global A-frag: 8 consecutive fp32 at [row][chunk*8] of row-major [.][64] -> bf16
__device__ inline short8 gfrag_f32(const float* __restrict__ base, int row, int chunk) {
    const float4* p = (const float4*)(base + row * 64 + chunk * 8);
    float4 a = p[0], b = p[1];
    short8 r;
    r[0] = (short)f2bf(a.x); r[1] = (short)f2bf(a.y); r[2] = (short)f2bf(a.z); r[3] = (short)f2bf(a.w);
    r[4] = (short)f2bf(b.x); r[5] = (short)f2bf(b.y); r[6] = (short)f2bf(b.z); r[7] = (short)f2bf(b.w);
    return r;
}

// coalesced stage: src [64][64] fp32 row-major -> bf16 swizzled LDS [64][128B] (mask 7)
__device__ inline void stage_rm(const float* __restrict__ src, char* dst, int t) {
    #pragma unroll
    for (int i = 0; i < 4; ++i) {
        int e = t + i * 256;                 // float4 idx 0..1023
        float4 x = ((const float4*)src)[e];
        int r = e >> 4;
        int c4 = (e & 15) * 4;
        ushort4v hv;
        hv[0] = f2bf(x.x); hv[1] = f2bf(x.y); hv[2] = f2bf(x.z); hv[3] = f2bf(x.w);
        *(ushort4v*)(dst + r * 128 + ((c4 * 2) ^ ((r & 7) << 4))) = hv;
    }
}

// coalesced transpose stage: src [64][64] fp32 row-major -> dst[j][i] bf16 swz (mask 7)
__device__ inline void stage_tr(const float* __restrict__ src, char* dst, int t) {
    int j = t & 63, g = t >> 6;
    #pragma unroll
    for (int i = 0; i < 4; ++i) {
        int i0 = g * 4 + i * 16;
        ushort4v hv;
        #pragma unroll
        for (int jj = 0; jj < 4; ++jj) hv[jj] = f2bf(src[(i0 + jj) * 64 + j]);
        *(ushort4v*)(dst + j * 128 + ((2 * i0) ^ ((j & 7) << 4))) = hv;
    }
}

// ---------------------------------------------------------------------------
// F1: per chunk (4 tiles): accumulate dS = sum_tiles v^T @ phi_k in f32 regs,
//     dZ = sum phi_k colsums. Write fp32 chunk deltas to wsC/wsZc.
// ---------------------------------------------------------------------------
__global__ __launch_bounds__(256) void passF1(const float* __restrict__ K,
                                              const float* __restrict__ V,
                                              const float* __restrict__ W,
                                              float* __restrict__ wsC,
                                              float* __restrict__ wsZc)
{
    __shared__ __align__(16) char lds[51200];
    char* kR  = lds;                     // [64 s][64 d] swz7
    char* vT0 = lds + 8192;              // [64 d][64 s] swz7 (double-buffered)
    char* vT1 = lds + 16384;
    char* WTl = lds + 24576;             // [64 f][64 d] swz7
    char* pT  = lds + 32768;             // [128 f][64 s] swz7
    float* Zp = (float*)(lds + 49152);   // [4 wv][128 f]

    const int t = threadIdx.x, wv = t >> 6, l = t & 63, lr = l & 15, lg = l >> 4;
    const int bid = blockIdx.x, bh = bid >> 4, c = bid & (CPB - 1), h = bh & (Hc - 1);
    const long hbase = (long)bh * (Lc * Dc);

    stage_tr(W + (long)h * (Dc * 64), WTl, t);

    f32x4 acc[8];
    #pragma unroll
    for (int i = 0; i < 8; ++i) acc[i] = zero4();
    float zpa[4] = {0.f,0.f,0.f,0.f}, zna[4] = {0.f,0.f,0.f,0.f};

    for (int tt = 0; tt < CH; ++tt) {
        char* vT = (tt & 1) ? vT1 : vT0;
        const long base = hbase + (long)(c * CH + tt) * (Sc * Dc);
        stage_rm(K + base, kR, t);
        stage_tr(V + base, vT, t);
        __syncthreads();                               // A

        short8 ak0 = ldfrag(kR, 16*wv + lr, lg, 128, 7);
        short8 ak1 = ldfrag(kR, 16*wv + lr, 4 + lg, 128, 7);
        f32x4 u0[4];
        #pragma unroll
        for (int tf = 0; tf < 4; ++tf) u0[tf] = zero4();
        #pragma unroll
        for (int tf = 0; tf < 4; ++tf) {
            u0[tf] = mfma(ak0, ldfrag(WTl, tf*16 + lr, lg, 128, 7), u0[tf]);
            u0[tf] = mfma(ak1, ldfrag(WTl, tf*16 + lr, 4 + lg, 128, 7), u0[tf]);
        }
        float pp[4][4], pn[4][4];
        #pragma unroll
        for (int r = 0; r < 4; ++r) {
            float sp = 0.f, sn = 0.f;
            #pragma unroll
            for (int tf = 0; tf < 4; ++tf) {
                pp[tf][r] = __expf(u0[tf][r]);  sp += pp[tf][r];
                pn[tf][r] = __expf(-u0[tf][r]); sn += pn[tf][r];
            }
            #pragma unroll
            for (int m = 1; m < 16; m <<= 1) { sp += __shfl_xor(sp, m, 16); sn += __shfl_xor(sn, m, 16); }
            float rp = 1.f / sp, rn = 1.f / sn;
            #pragma unroll
            for (int tf = 0; tf < 4; ++tf) {
                pp[tf][r] *= rp; pn[tf][r] *= rn;
                zpa[tf] += pp[tf][r]; zna[tf] += pn[tf][r];
            }
        }
        #pragma unroll
        for (int tf = 0; tf < 4; ++tf)
            #pragma unroll
            for (int r = 0; r < 4; ++r) {
                int s = 16*wv + lg*4 + r;
                int f = tf*16 + lr;
                *(ushort*)(pT + f*128 + ((2*s) ^ ((f & 7) << 4))) = f2bf(pp[tf][r]);
                int fn = 64 + f;
                *(ushort*)(pT + fn*128 + ((2*s) ^ ((fn & 7) << 4))) = f2bf(pn[tf][r]);
            }
        __syncthreads();                               // B

        short8 av0 = ldfrag(vT, 16*wv + lr, lg, 128, 7);
        short8 av1 = ldfrag(vT, 16*wv + lr, 4 + lg, 128, 7);
        #pragma unroll
        for (int tf = 0; tf < 8; ++tf) {
            acc[tf] = mfma(av0, ldfrag(pT, tf*16 + lr, lg, 128, 7), acc[tf]);
            acc[tf] = mfma(av1, ldfrag(pT, tf*16 + lr, 4 + lg, 128, 7), acc[tf]);
        }
    }

    float* oc = wsC + (long)bid * 8192;     // [64 d][128 f]
    #pragma unroll
    for (int tf = 0; tf < 8; ++tf)
        #pragma unroll
        for (int r = 0; r < 4; ++r)
            oc[(16*wv + lg*4 + r) * 128 + tf*16 + lr] = acc[tf][r];

    #pragma unroll
    for (int tf = 0; tf < 4; ++tf) {
        zpa[tf] += __shfl_xor(zpa[tf], 16); zpa[tf] += __shfl_xor(zpa[tf], 32);
        zna[tf] += __shfl_xor(zna[tf], 16); zna[tf] += __shfl_xor(zna[tf], 32);
    }
    if (l < 16) {
        #pragma unroll
        for (int tf = 0; tf < 4; ++tf) {
            Zp[wv*128 + tf*16 + lr]      = zpa[tf];
            Zp[wv*128 + 64 + tf*16 + lr] = zna[tf];
        }
    }
    __syncthreads();
    if (t < 128)
        wsZc[(long)bid * 128 + t] = Zp[t] + Zp[128 + t] + Zp[256 + t] + Zp[384 + t];
}

// ---------------------------------------------------------------------------
// F2: exclusive prefix over the 16 chunks of each (b,h), register-batched.
// blocks 0..255: S-part (each owns 1024 floats); 256..287: Z-part.
// ---------------------------------------------------------------------------
__global__ __launch_bounds__(256) void passF2(float* __restrict__ wsC,
                                              float* __restrict__ wsZc)
{
    const int t = threadIdx.x;
    if (blockIdx.x >= 256) {
        const int bh = blockIdx.x - 256;
        if (t < 128) {
            float* zp = wsZc + (long)bh * CPB * 128 + t;
            float buf[CPB];
            #pragma unroll
            for (int i = 0; i < CPB; ++i) buf[i] = zp[(long)i * 128];
            float cz = 0.f;
            #pragma unroll
            for (int i = 0; i < CPB; ++i) { float x = buf[i]; zp[(long)i * 128] = cz; cz += x; }
        }
        return;
    }
    const int bh = blockIdx.x >> 3, part = blockIdx.x & 7;
    float* p = wsC + (long)bh * CPB * 8192 + part * 1024 + t * 4;
    float4 buf[CPB];
    #pragma unroll
    for (int i = 0; i < CPB; ++i) buf[i] = *(const float4*)(p + (long)i * 8192);
    float4 cr = make_float4(0.f, 0.f, 0.f, 0.f);
    #pragma unroll
    for (int i = 0; i < CPB; ++i) {
        float4 x = buf[i];
        *(float4*)(p + (long)i * 8192) = cr;
        cr.x += x.x; cr.y += x.y; cr.z += x.z; cr.w += x.w;
    }
}

// ---------------------------------------------------------------------------
// F3: per chunk: replay 4 tiles with running state in f32 MFMA accumulators.
// Per tile: Stb(bf16)<-sacc; stage k,v; u_q,u_k,scores MFMA; softmaxes;
// out = (w*aV + phi_q@S)/den; then state update sacc += v^T@phi_k.
// ---------------------------------------------------------------------------
__global__ __launch_bounds__(256) void passF3(const float* __restrict__ Q,
                                              const float* __restrict__ K,
                                              const float* __restrict__ V,
                                              const float* __restrict__ W,
                                              const float* __restrict__ Alpha,
                                              const float* __restrict__ wsC,
                                              const float* __restrict__ wsZc,
                                              float* __restrict__ Out)
{
    __shared__ __align__(16) char lds[75776];
    char* kR   = lds;                    // 8K  [64 s][64 d] swz7
    char* vT0  = lds + 8192;             // 8K  [64 d][64 s] swz7 (double-buffered)
    char* vT1  = lds + 16384;            // 8K
    char* WTl  = lds + 24576;            // 8K  [64 f][64 d] swz7
    char* Stb  = lds + 32768;            // 16K [64 d][128 f] swz15 (pre-state bf16)
    char* phiP = lds + 49152;            // 16K per-wave phi_q slices; pT overlay
    char* aLb  = lds + 65536;            // 8K  per-wave a slices
    float* Zp  = (float*)(lds + 73728);  // 2K [4 wv][128 f]

    const int t = threadIdx.x, wv = t >> 6, l = t & 63, lr = l & 15, lg = l >> 4;
    char* phiL = phiP + wv * 4096;       // [16 s][256B] swz15
    char* aL   = aLb + wv * 2048;        // [16 s][128B] swz7
    char* pT   = phiP;                   // overlay: [128 f][64 s] swz7

    const int bid = blockIdx.x, bh = bid >> 4, c = bid & (CPB - 1), h = bh & (Hc - 1);
    const long hbase = (long)bh * (Lc * Dc);

    stage_tr(W + (long)h * (Dc * 64), WTl, t);

    // running pre-state (chunk-exclusive prefix), f32 in MFMA acc layout
    f32x4 sacc[8];
    {
        const float* s0p = wsC + (long)bid * 8192;
        #pragma unroll
        for (int tf = 0; tf < 8; ++tf)
            #pragma unroll
            for (int r = 0; r < 4; ++r)
                sacc[tf][r] = s0p[(16*wv + lg*4 + r) * 128 + tf*16 + lr];
    }
    float zv[4], zn_[4];
    {
        const float* z0 = wsZc + (long)bid * 128;
        #pragma unroll
        for (int tf = 0; tf < 4; ++tf) { zv[tf] = z0[tf*16 + lr]; zn_[tf] = z0[64 + tf*16 + lr]; }
    }
    const float w = 1.f / (1.f + __expf(-Alpha[h]));

    for (int tt = 0; tt < CH; ++tt) {
        char* vT = (tt & 1) ? vT1 : vT0;
        const long base = hbase + (long)(c * CH + tt) * (Sc * Dc);

        // ---- phase 1: pre-state to LDS; stage k,v; q A-frags from global
        #pragma unroll
        for (int tf = 0; tf < 8; ++tf)
            #pragma unroll
            for (int r = 0; r < 4; ++r) {
                int d = 16*wv + lg*4 + r;
                int f = tf*16 + lr;
                *(ushort*)(Stb + d*256 + ((2*f) ^ ((d & 15) << 4))) = f2bf(sacc[tf][r]);
            }
        stage_rm(K + base, kR, t);
        stage_tr(V + base, vT, t);
        short8 aq0 = gfrag_f32(Q + base, 16*wv + lr, lg);
        short8 aq1 = gfrag_f32(Q + base, 16*wv + lr, 4 + lg);
        __syncthreads();                               // A

        // ---- phase 2: MFMAs + softmaxes + output
        short8 ak0 = ldfrag(kR, 16*wv + lr, lg, 128, 7);
        short8 ak1 = ldfrag(kR, 16*wv + lr, 4 + lg, 128, 7);
        f32x4 uq[4], uk[4], sc0[4];
        #pragma unroll
        for (int tf = 0; tf < 4; ++tf) { uq[tf] = zero4(); uk[tf] = zero4(); sc0[tf] = zero4(); }
        const bool upd = (tt != CH - 1);
        #pragma unroll
        for (int tf = 0; tf < 4; ++tf) {
            short8 bw0 = ldfrag(WTl, tf*16 + lr, lg, 128, 7);
            short8 bw1 = ldfrag(WTl, tf*16 + lr, 4 + lg, 128, 7);
            uq[tf] = mfma(aq0, bw0, uq[tf]); uq[tf] = mfma(aq1, bw1, uq[tf]);
            sc0[tf] = mfma(aq0, ldfrag(kR, tf*16 + lr, lg, 128, 7), sc0[tf]);
            sc0[tf] = mfma(aq1, ldfrag(kR, tf*16 + lr, 4 + lg, 128, 7), sc0[tf]);
            if (upd) { uk[tf] = mfma(ak0, bw0, uk[tf]); uk[tf] = mfma(ak1, bw1, uk[tf]); }
        }

        // phi_q (normalized softmax pair, max-sub skipped: invariant) + lden + phiL
        float lden[4], sden[4];
        #pragma unroll
        for (int r = 0; r < 4; ++r) {
            float pqp[4], pqn[4];
            float sp = 0.f, sn = 0.f;
            #pragma unroll
            for (int tf = 0; tf < 4; ++tf) {
                pqp[tf] = __expf(uq[tf][r]);  sp += pqp[tf];
                pqn[tf] = __expf(-uq[tf][r]); sn += pqn[tf];
            }
            #pragma unroll
            for (int m = 1; m < 16; m <<= 1) { sp += __shfl_xor(sp, m, 16); sn += __shfl_xor(sn, m, 16); }
            float rp = 1.f / sp, rn = 1.f / sn;
            float zd = 0.f;
            #pragma unroll
            for (int tf = 0; tf < 4; ++tf) {
                pqp[tf] *= rp; pqn[tf] *= rn;
                zd += pqp[tf] * zv[tf] + pqn[tf] * zn_[tf];
            }
            #pragma unroll
            for (int m = 1; m < 16; m <<= 1) zd += __shfl_xor(zd, m, 16);
            lden[r] = fmaxf(zd, EPSf);
            int sl = lg*4 + r;
            #pragma unroll
            for (int tf = 0; tf < 4; ++tf) {
                int f = tf*16 + lr;
                *(ushort*)(phiL + sl*256 + ((2*f) ^ ((sl & 15) << 4))) = f2bf(pqp[tf]);
                *(ushort*)(phiL + sl*256 + ((2*(64 + f)) ^ ((sl & 15) << 4))) = f2bf(pqn[tf]);
            }
        }

        // scores softmax (true row max required by reference) ; a pre-scaled by w
        #pragma unroll
        for (int r = 0; r < 4; ++r) {
            float s[4];
            #pragma unroll
            for (int tf = 0; tf < 4; ++tf) s[tf] = sc0[tf][r] * SCALE;
            float m2 = fmaxf(fmaxf(s[0], s[1]), fmaxf(s[2], s[3]));
            #pragma unroll
            for (int m = 1; m < 16; m <<= 1) m2 = fmaxf(m2, __shfl_xor(m2, m, 16));
            float as = 0.f;
            #pragma unroll
            for (int tf = 0; tf < 4; ++tf) { s[tf] = __expf(s[tf] - m2); as += s[tf]; }
            #pragma unroll
            for (int m = 1; m < 16; m <<= 1) as += __shfl_xor(as, m, 16);
            sden[r] = fmaxf(as, EPSf);
            int sl = lg*4 + r;
            #pragma unroll
            for (int tf = 0; tf < 4; ++tf)
                *(ushort*)(aL + sl*128 + ((2*(tf*16 + lr)) ^ ((sl & 7) << 4))) = f2bf(w * s[tf]);
        }

        // out = (w*(a@v) + phi_q@S) / den
        f32x4 oacc[4];
        #pragma unroll
        for (int td = 0; td < 4; ++td) oacc[td] = zero4();
        short8 aa0 = ldfrag(aL, lr, lg, 128, 7);
        short8 aa1 = ldfrag(aL, lr, 4 + lg, 128, 7);
        #pragma unroll
        for (int td = 0; td < 4; ++td) {
            oacc[td] = mfma(aa0, ldfrag(vT, td*16 + lr, lg, 128, 7), oacc[td]);
            oacc[td] = mfma(aa1, ldfrag(vT, td*16 + lr, 4 + lg, 128, 7), oacc[td]);
        }
        short8 pf[4];
        #pragma unroll
        for (int kc = 0; kc < 4; ++kc) pf[kc] = ldfrag(phiL, lr, kc*4 + lg, 256, 15);
        #pragma unroll
        for (int td = 0; td < 4; ++td)
            #pragma unroll
            for (int kc = 0; kc < 4; ++kc)
                oacc[td] = mfma(pf[kc], ldfrag(Stb, td*16 + lr, kc*4 + lg, 256, 15), oacc[td]);

        float* op = Out + base;
        #pragma unroll
        for (int r = 0; r < 4; ++r) {
            int s = 16*wv + lg*4 + r;
            float inv = 1.f / fmaxf(w * sden[r] + lden[r], EPSf);
            #pragma unroll
            for (int td = 0; td < 4; ++td)
                op[s*64 + td*16 + lr] = oacc[td][r] * inv;
        }

        // ---- phase 2b + 3: state update (skipped after last tile)
        if (upd) {
            __syncthreads();                           // A2: phiL reads done -> pT overlay
            float pkp[4][4], pkn[4][4];
            float zr[4] = {0.f,0.f,0.f,0.f}, zrn[4] = {0.f,0.f,0.f,0.f};
            #pragma unroll
            for (int r = 0; r < 4; ++r) {
                float sp = 0.f, sn = 0.f;
                #pragma unroll
                for (int tf = 0; tf < 4; ++tf) {
                    pkp[tf][r] = __expf(uk[tf][r]);  sp += pkp[tf][r];
                    pkn[tf][r] = __expf(-uk[tf][r]); sn += pkn[tf][r];
                }
                #pragma unroll
                for (int m = 1; m < 16; m <<= 1) { sp += __shfl_xor(sp, m, 16); sn += __shfl_xor(sn, m, 16); }
                float rp = 1.f / sp, rn = 1.f / sn;
                #pragma unroll
                for (int tf = 0; tf < 4; ++tf) {
                    pkp[tf][r] *= rp; pkn[tf][r] *= rn;
                    zr[tf] += pkp[tf][r]; zrn[tf] += pkn[tf][r];
                }
            }
            #pragma unroll
            for (int tf = 0; tf < 4; ++tf)
                #pragma unroll
                for (int r = 0; r < 4; ++r) {
                    int s = 16*wv + lg*4 + r;
                    int f = tf*16 + lr;
                    *(ushort*)(pT + f*128 + ((2*s) ^ ((f & 7) << 4))) = f2bf(pkp[tf][r]);
                    int fn = 64 + f;
                    *(ushort*)(pT + fn*128 + ((2*s) ^ ((fn & 7) << 4))) = f2bf(pkn[tf][r]);
                }
            #pragma unroll
            for (int tf = 0; tf < 4; ++tf) {
                zr[tf] += __shfl_xor(zr[tf], 16);  zr[tf] += __shfl_xor(zr[tf], 32);
                zrn[tf] += __shfl_xor(zrn[tf], 16); zrn[tf] += __shfl_xor(zrn[tf], 32);
            }
            if (l < 16) {
                #pragma unroll
                for (int tf = 0; tf < 4; ++tf) {
                    Zp[wv*128 + tf*16 + lr]      = zr[tf];
                    Zp[wv*128 + 64 + tf*16 + lr] = zrn[tf];
                }
            }
            __syncthreads();                           // B
            short8 av0 = ldfrag(vT, 16*wv + lr, lg, 128, 7);
            short8 av1 = ldfrag(vT, 16*wv + lr, 4 + lg, 128, 7);
            #pragma unroll
            for (int tf = 0; tf < 8; ++tf) {
                sacc[tf] = mfma(av0, ldfrag(pT, tf*16 + lr, lg, 128, 7), sacc[tf]);
                sacc[tf] = mfma(av1, ldfrag(pT, tf*16 + lr, 4 + lg, 128, 7), sacc[tf]);
            }
            #pragma unroll
            for (int tf = 0; tf < 4; ++tf) {
                int f = tf*16 + lr;
                zv[tf]  += Zp[f] + Zp[128 + f] + Zp[256 + f] + Zp[384 + f];
                zn_[tf] += Zp[64 + f] + Zp[192 + f] + Zp[320 + f] + Zp[448 + f];
            }
        }
    }
}

// ---------------------------------------------------------------------------
extern "C" void kernel_launch(void* const* d_in, const int* in_sizes, int n_in,
                              void* d_out, int out_size, void* d_ws, size_t ws_size,
                              hipStream_t stream)
{
    const float* q     = (const float*)d_in[0];
    const float* k     = (const float*)d_in[1];
    const float* v     = (const float*)d_in[2];
    const float* W     = (const float*)d_in[3];
    const float* alpha = (const float*)d_in[4];
    float* out = (float*)d_out;

    float* wsC  = (float*)d_ws;                                    // 512*8192 f32 = 16.8 MB
    float* wsZc = wsC + (size_t)NCHUNK * 8192;                     // 512*128 f32 = 256 KB

    passF1<<<NCHUNK, 256, 0, stream>>>(k, v, W, wsC, wsZc);
    passF2<<<288, 256, 0, stream>>>(wsC, wsZc);
    passF3<<<NCHUNK, 256, 0, stream>>>(q, k, v, W, alpha, wsC, wsZc, out);
}

// Round 5
// 71.655 us; speedup vs baseline: 1.4601x; 1.4601x over previous
//
#include <hip/hip_runtime.h>
#include <hip/hip_bf16.h>
#include <math.h>

// BlockSoftmaxLinearHybrid: B=2,H=16,L=4096,D=64,F=64,S=64
constexpr int Hc = 16, Lc = 4096, Dc = 64;
constexpr int Nc = 64;             // tiles along L per (b,h)
constexpr int F2 = 128;
constexpr int NBLK = 2048;         // 32 bh * 64 tiles
constexpr float EPSf = 1e-6f;
constexpr float SCALE = 0.125f;    // D^-0.5

typedef short short8 __attribute__((ext_vector_type(8)));     // 8 bf16 MFMA A/B frag
typedef float f32x4 __attribute__((ext_vector_type(4)));      // MFMA C/D frag
typedef unsigned short ushort;
typedef ushort ushort4v __attribute__((ext_vector_type(4)));

__device__ inline ushort f2bf(float x) {           // native cvt (fuses to v_cvt_pk_bf16_f32)
    return __builtin_bit_cast(ushort, __float2bfloat16(x));
}
__device__ inline float bf2f(ushort h) {
    return __builtin_bit_cast(float, ((unsigned)h) << 16);
}
__device__ inline f32x4 zero4() { f32x4 z = {0.f, 0.f, 0.f, 0.f}; return z; }

// MFMA 16x16x32 bf16 (verified layout set):
//  A frag: lane reads A[row0+(l&15)][chunk*8 + (l>>4)*8-pattern via chunks lg,4+lg]
//  B frag: from Bt[col][k] identically; D: row = row0+(l>>4)*4+reg, col = col0+(l&15)
__device__ inline f32x4 mfma(short8 a, short8 b, f32x4 c) {
    return __builtin_amdgcn_mfma_f32_16x16x32_bf16(a, b, c, 0, 0, 0);
}

// LDS fragment read, XOR-swizzled 16B chunks (T2)
__device__ inline short8 ldfrag(const char* L, int row, int chunk, int rowbytes, int mask) {
    return *(const short8*)(L + row * rowbytes + ((chunk * 16) ^ ((row & mask) << 4)));
}

// Direct global frag: 8 consecutive fp32 at [row][chunk*8] of row-major [.][64] -> bf16
__device__ inline short8 gfrag_f32(const float* __restrict__ base, int row, int chunk) {
    const float4* p = (const float4*)(base + row * 64 + chunk * 8);
    float4 a = p[0], b = p[1];
    short8 r;
    r[0] = (short)f2bf(a.x); r[1] = (short)f2bf(a.y); r[2] = (short)f2bf(a.z); r[3] = (short)f2bf(a.w);
    r[4] = (short)f2bf(b.x); r[5] = (short)f2bf(b.y); r[6] = (short)f2bf(b.z); r[7] = (short)f2bf(b.w);
    return r;
}
// Direct global frag from bf16 row-major [.][rowlen]
__device__ inline short8 gfrag_bf16(const ushort* __restrict__ base, int row, int chunk, int rowlen) {
    return *(const short8*)(base + row * rowlen + chunk * 8);
}

// coalesced stage: [64][64] fp32 row-major -> bf16 swizzled LDS [64 rows][128B] (mask 7)
__device__ inline void stage_rm(const float* __restrict__ src, char* dst, int t) {
    #pragma unroll
    for (int i = 0; i < 4; ++i) {
        int e = t + i * 256;
        float4 x = ((const float4*)src)[e];
        int r = e >> 4;
        int c4 = (e & 15) * 4;
        ushort4v hv;
        hv[0] = f2bf(x.x); hv[1] = f2bf(x.y); hv[2] = f2bf(x.z); hv[3] = f2bf(x.w);
        *(ushort4v*)(dst + r * 128 + ((c4 * 2) ^ ((r & 7) << 4))) = hv;
    }
}

// coalesced transpose stage: [64][64] fp32 -> dst[j][i] bf16 swz (mask 7)
__device__ inline void stage_tr(const float* __restrict__ src, char* dst, int t) {
    int j = t & 63, g = t >> 6;
    #pragma unroll
    for (int i = 0; i < 4; ++i) {
        int i0 = g * 4 + i * 16;
        ushort4v hv;
        #pragma unroll
        for (int jj = 0; jj < 4; ++jj) hv[jj] = f2bf(src[(i0 + jj) * 64 + j]);
        *(ushort4v*)(dst + j * 128 + ((2 * i0) ^ ((j & 7) << 4))) = hv;
    }
}

// ---------------------------------------------------------------------------
// passW: Wt[h][f][d] = bf16(W[h][d][f])
// ---------------------------------------------------------------------------
__global__ __launch_bounds__(256) void passW(const float* __restrict__ W,
                                             ushort* __restrict__ Wt)
{
    const int h = blockIdx.x, t = threadIdx.x;
    const int f = t & 63, g = t >> 6;
    const float* src = W + (long)h * 4096;
    ushort* dst = Wt + (long)h * 4096;
    #pragma unroll
    for (int i = 0; i < 16; ++i) {
        int d = g * 16 + i;
        dst[f * 64 + d] = f2bf(src[d * 64 + f]);
    }
}

// ---------------------------------------------------------------------------
// passA: phi(k) (u-layout D[s][f]); dSt[d][f] = v^T @ phi_k -> wsS bf16;
//        dZ[f] -> wsZ fp32. ONE barrier. LDS 26.5K -> 6 blocks/CU.
// ---------------------------------------------------------------------------
__global__ __launch_bounds__(256) void passA(const float* __restrict__ K,
                                             const float* __restrict__ V,
                                             const ushort* __restrict__ Wt,
                                             ushort* __restrict__ wsS,
                                             float* __restrict__ wsZ)
{
    __shared__ __align__(16) char lds[26624];
    char* vT = lds;                      // [64 d][64 s] swz7
    char* pT = lds + 8192;               // [128 f][64 s] swz7
    float* Zp = (float*)(lds + 24576);   // [4 wv][128 f]

    const int t = threadIdx.x, wv = t >> 6, l = t & 63, lr = l & 15, lg = l >> 4;
    const int bid = blockIdx.x, bh = bid >> 6, h = bh & (Hc - 1);
    const long base = (long)bh * (Lc * Dc) + (long)(bid & 63) * (64 * Dc);

    stage_tr(V + base, vT, t);

    const float* kp = K + base;
    const ushort* wt = Wt + (long)h * 4096;

    // u = k @ W : A = k rows (global), B = Wt cols (global bf16)
    short8 ak0 = gfrag_f32(kp, 16 * wv + lr, lg);
    short8 ak1 = gfrag_f32(kp, 16 * wv + lr, 4 + lg);
    f32x4 u0[4];
    #pragma unroll
    for (int tf = 0; tf < 4; ++tf) u0[tf] = zero4();
    #pragma unroll
    for (int tf = 0; tf < 4; ++tf) {
        u0[tf] = mfma(ak0, gfrag_bf16(wt, tf * 16 + lr, lg, 64), u0[tf]);
        u0[tf] = mfma(ak1, gfrag_bf16(wt, tf * 16 + lr, 4 + lg, 64), u0[tf]);
    }

    // dual softmax over f (no max-sub needed: |u| small, softmax invariant)
    float pp[4][4], pn[4][4];
    float zpa[4] = {0.f,0.f,0.f,0.f}, zna[4] = {0.f,0.f,0.f,0.f};
    #pragma unroll
    for (int r = 0; r < 4; ++r) {
        float sp = 0.f, sn = 0.f;
        #pragma unroll
        for (int tf = 0; tf < 4; ++tf) {
            pp[tf][r] = __expf(u0[tf][r]);  sp += pp[tf][r];
            pn[tf][r] = __expf(-u0[tf][r]); sn += pn[tf][r];
        }
        #pragma unroll
        for (int m = 1; m < 16; m <<= 1) { sp += __shfl_xor(sp, m, 16); sn += __shfl_xor(sn, m, 16); }
        float rp = 1.f / sp, rn = 1.f / sn;
        #pragma unroll
        for (int tf = 0; tf < 4; ++tf) {
            pp[tf][r] *= rp; pn[tf][r] *= rn;
            zpa[tf] += pp[tf][r]; zna[tf] += pn[tf][r];
        }
    }

    // packed phi_k^T writes: pT[f][s], 4 consecutive s per (tf) -> ds_write_b64
    const int s0 = 16 * wv + lg * 4;
    #pragma unroll
    for (int tf = 0; tf < 4; ++tf) {
        int f = tf * 16 + lr;
        ushort4v hp, hn;
        #pragma unroll
        for (int r = 0; r < 4; ++r) { hp[r] = f2bf(pp[tf][r]); hn[r] = f2bf(pn[tf][r]); }
        *(ushort4v*)(pT + f * 128 + ((2 * s0) ^ ((f & 7) << 4))) = hp;
        int fn = 64 + f;
        *(ushort4v*)(pT + fn * 128 + ((2 * s0) ^ ((fn & 7) << 4))) = hn;
    }
    // Z partials (per wave)
    #pragma unroll
    for (int tf = 0; tf < 4; ++tf) {
        zpa[tf] += __shfl_xor(zpa[tf], 16); zpa[tf] += __shfl_xor(zpa[tf], 32);
        zna[tf] += __shfl_xor(zna[tf], 16); zna[tf] += __shfl_xor(zna[tf], 32);
    }
    if (l < 16) {
        #pragma unroll
        for (int tf = 0; tf < 4; ++tf) {
            Zp[wv * 128 + tf * 16 + lr]      = zpa[tf];
            Zp[wv * 128 + 64 + tf * 16 + lr] = zna[tf];
        }
    }
    __syncthreads();

    // dSt[d][f] = v^T @ phi_k
    short8 av0 = ldfrag(vT, 16 * wv + lr, lg, 128, 7);
    short8 av1 = ldfrag(vT, 16 * wv + lr, 4 + lg, 128, 7);
    f32x4 acc[8];
    #pragma unroll
    for (int tf = 0; tf < 8; ++tf) acc[tf] = zero4();
    #pragma unroll
    for (int tf = 0; tf < 8; ++tf) {
        acc[tf] = mfma(av0, ldfrag(pT, tf * 16 + lr, lg, 128, 7), acc[tf]);
        acc[tf] = mfma(av1, ldfrag(pT, tf * 16 + lr, 4 + lg, 128, 7), acc[tf]);
    }
    ushort* o = wsS + (long)bid * (F2 * Dc);
    #pragma unroll
    for (int tf = 0; tf < 8; ++tf)
        #pragma unroll
        for (int r = 0; r < 4; ++r) {
            int d = 16 * wv + lg * 4 + r;
            o[d * 128 + tf * 16 + lr] = f2bf(acc[tf][r]);
        }

    if (t < 128)
        wsZ[(long)bid * F2 + t] = Zp[t] + Zp[128 + t] + Zp[256 + t] + Zp[384 + t];
}

// ---------------------------------------------------------------------------
// passB: exclusive prefix over n per bh; register-batched (32 loads in flight).
// ---------------------------------------------------------------------------
__global__ __launch_bounds__(256) void passB(ushort* __restrict__ wsS,
                                             float* __restrict__ wsZ)
{
    const int t = threadIdx.x;
    if (blockIdx.x >= 256) {                 // Z prefix
        const int bh = blockIdx.x - 256;
        if (t < 128) {
            float zc = 0.f, zb[32];
            #pragma unroll
            for (int h2 = 0; h2 < 2; ++h2) {
                float* zp = wsZ + ((long)bh * 64 + h2 * 32) * 128 + t;
                #pragma unroll
                for (int i = 0; i < 32; ++i) zb[i] = zp[i * 128];
                #pragma unroll
                for (int i = 0; i < 32; ++i) { float x = zb[i]; zp[i * 128] = zc; zc += x; }
            }
        }
        return;
    }
    const int bh = blockIdx.x >> 3, chunk = blockIdx.x & 7;
    ushort* p = wsS + (long)bh * 64 * 8192 + chunk * 1024 + t * 4;
    float c0 = 0.f, c1 = 0.f, c2 = 0.f, c3 = 0.f;
    ushort4v buf[32];
    #pragma unroll
    for (int h2 = 0; h2 < 2; ++h2) {
        ushort4v* pp = (ushort4v*)(p + (long)h2 * 32 * 8192);
        #pragma unroll
        for (int i = 0; i < 32; ++i) buf[i] = pp[i * 2048];
        #pragma unroll
        for (int i = 0; i < 32; ++i) {
            ushort4v x = buf[i];
            ushort4v cc;
            cc[0] = f2bf(c0); cc[1] = f2bf(c1); cc[2] = f2bf(c2); cc[3] = f2bf(c3);
            pp[i * 2048] = cc;
            c0 += bf2f(x[0]); c1 += bf2f(x[1]); c2 += bf2f(x[2]); c3 += bf2f(x[3]);
        }
    }
}

// ---------------------------------------------------------------------------
// passC: transposed compute (u^T, scores^T) so each lane owns ONE row;
// 2-step reductions, packed ds_write_b64 frag writes, 2 barriers, 49.7K LDS.
// ---------------------------------------------------------------------------
__global__ __launch_bounds__(256) void passC(const float* __restrict__ Q,
                                             const float* __restrict__ K,
                                             const float* __restrict__ V,
                                             const ushort* __restrict__ Wt,
                                             const float* __restrict__ Alpha,
                                             const ushort* __restrict__ wsS,
                                             const float* __restrict__ wsZ,
                                             float* __restrict__ Out)
{
    __shared__ __align__(16) char lds[49664];
    char* kR    = lds;                   // stage1: [64 t][64 d] swz7
    char* phiAB = lds;                   // stage2 (after barrier B): [64 s][128 f] swz15
    char* vT    = lds + 16384;           // [64 d][64 t] swz7
    char* St    = lds + 24576;           // [64 d][128 f] swz15 (S^T bf16)
    char* aAB   = lds + 40960;           // [64 s][64 t] swz7
    float* sZ   = (float*)(lds + 49152); // [128]

    const int t = threadIdx.x, wv = t >> 6, l = t & 63, lr = l & 15, lg = l >> 4;
    const int bid = blockIdx.x, bh = bid >> 6, h = bh & (Hc - 1);
    const long base = (long)bh * (Lc * Dc) + (long)(bid & 63) * (64 * Dc);
    const int s = 16 * wv + lr;          // this lane's owned row

    // ---- global fragment loads (issue first)
    const float* qp = Q + base;
    short8 bq0 = gfrag_f32(qp, s, lg);           // q B-frags (own rows)
    short8 bq1 = gfrag_f32(qp, s, 4 + lg);
    const ushort* wt = Wt + (long)h * 4096;
    short8 aw[4][2];
    #pragma unroll
    for (int tf = 0; tf < 4; ++tf) {
        aw[tf][0] = gfrag_bf16(wt, tf * 16 + lr, lg, 64);
        aw[tf][1] = gfrag_bf16(wt, tf * 16 + lr, 4 + lg, 64);
    }

    // ---- stages
    {   // S^T tile bf16 -> swizzled LDS
        const short8* Sg8 = (const short8*)(wsS + (long)bid * 8192);
        #pragma unroll
        for (int i = 0; i < 4; ++i) {
            int c = t + i * 256;
            int d = c >> 4, fc = c & 15;
            *(short8*)(St + d * 256 + ((fc * 16) ^ ((d & 15) << 4))) = Sg8[c];
        }
    }
    stage_rm(K + base, kR, t);
    stage_tr(V + base, vT, t);
    if (t < 128) sZ[t] = wsZ[(long)bid * 128 + t];

    // ---- pre-barrier: u^T = mfma(A=Wt rows f, B=q cols s) -> D[f][s]
    f32x4 uq[4];
    #pragma unroll
    for (int tf = 0; tf < 4; ++tf) uq[tf] = zero4();
    #pragma unroll
    for (int tf = 0; tf < 4; ++tf) {
        uq[tf] = mfma(aw[tf][0], bq0, uq[tf]);
        uq[tf] = mfma(aw[tf][1], bq1, uq[tf]);
    }
    // phi softmax over f for row s: in-lane(16) + xor16 + xor32
    float sp = 0.f, sn = 0.f;
    float pqp[4][4], pqn[4][4];
    #pragma unroll
    for (int tf = 0; tf < 4; ++tf)
        #pragma unroll
        for (int r = 0; r < 4; ++r) {
            pqp[tf][r] = __expf(uq[tf][r]);  sp += pqp[tf][r];
            pqn[tf][r] = __expf(-uq[tf][r]); sn += pqn[tf][r];
        }
    sp += __shfl_xor(sp, 16); sp += __shfl_xor(sp, 32);
    sn += __shfl_xor(sn, 16); sn += __shfl_xor(sn, 32);
    {
        float rp = 1.f / sp, rn = 1.f / sn;
        #pragma unroll
        for (int tf = 0; tf < 4; ++tf)
            #pragma unroll
            for (int r = 0; r < 4; ++r) { pqp[tf][r] *= rp; pqn[tf][r] *= rn; }
    }
    // pack phi to bf16 (kept in regs; fp32 copies released)
    ushort4v phk[4], phkn[4];
    #pragma unroll
    for (int tf = 0; tf < 4; ++tf)
        #pragma unroll
        for (int r = 0; r < 4; ++r) { phk[tf][r] = f2bf(pqp[tf][r]); phkn[tf][r] = f2bf(pqn[tf][r]); }

    const float w = 1.f / (1.f + __expf(-Alpha[h]));

    __syncthreads();                                   // A: stages ready

    // ---- scores^T = mfma(A=k rows t, B=q cols s) -> D[t][s]
    f32x4 sc[4];
    #pragma unroll
    for (int tt = 0; tt < 4; ++tt) sc[tt] = zero4();
    #pragma unroll
    for (int tt = 0; tt < 4; ++tt) {
        sc[tt] = mfma(ldfrag(kR, tt * 16 + lr, lg, 128, 7), bq0, sc[tt]);
        sc[tt] = mfma(ldfrag(kR, tt * 16 + lr, 4 + lg, 128, 7), bq1, sc[tt]);
    }
    // row max (exact, required) + exp-sum for row s
    #pragma unroll
    for (int tt = 0; tt < 4; ++tt)
        #pragma unroll
        for (int r = 0; r < 4; ++r) sc[tt][r] *= SCALE;
    float m2;
    {
        float m01 = fmaxf(fmaxf(fmaxf(sc[0][0], sc[0][1]), fmaxf(sc[0][2], sc[0][3])),
                          fmaxf(fmaxf(sc[1][0], sc[1][1]), fmaxf(sc[1][2], sc[1][3])));
        float m23 = fmaxf(fmaxf(fmaxf(sc[2][0], sc[2][1]), fmaxf(sc[2][2], sc[2][3])),
                          fmaxf(fmaxf(sc[3][0], sc[3][1]), fmaxf(sc[3][2], sc[3][3])));
        m2 = fmaxf(m01, m23);
        m2 = fmaxf(m2, __shfl_xor(m2, 16));
        m2 = fmaxf(m2, __shfl_xor(m2, 32));
    }
    float as = 0.f;
    ushort4v apk[4];
    #pragma unroll
    for (int tt = 0; tt < 4; ++tt)
        #pragma unroll
        for (int r = 0; r < 4; ++r) {
            float e = __expf(sc[tt][r] - m2);
            as += e;
            apk[tt][r] = f2bf(w * e);                  // bake w into numerator operand
        }
    as += __shfl_xor(as, 16); as += __shfl_xor(as, 32);
    const float sden = fmaxf(as, EPSf);

    // lden = max(phi . Z, EPS), using the SAME bf16 phi as the MFMA operand
    float zd = 0.f;
    #pragma unroll
    for (int tf = 0; tf < 4; ++tf)
        #pragma unroll
        for (int r = 0; r < 4; ++r) {
            int f = tf * 16 + lg * 4 + r;
            zd += bf2f(phk[tf][r]) * sZ[f] + bf2f(phkn[tf][r]) * sZ[64 + f];
        }
    zd += __shfl_xor(zd, 16); zd += __shfl_xor(zd, 32);
    const float lden = fmaxf(zd, EPSf);
    const float inv = 1.f / fmaxf(w * sden + lden, EPSf);

    // a writes (region not overlaid -> no barrier needed)
    #pragma unroll
    for (int tt = 0; tt < 4; ++tt)
        *(ushort4v*)(aAB + s * 128 + ((32 * tt + 8 * lg) ^ ((s & 7) << 4))) = apk[tt];

    __syncthreads();                                   // B: all kR reads done

    // phi writes (overlay kR region), packed 8B
    #pragma unroll
    for (int tf = 0; tf < 4; ++tf) {
        *(ushort4v*)(phiAB + s * 256 + ((32 * tf + 8 * lg) ^ ((s & 15) << 4))) = phk[tf];
        *(ushort4v*)(phiAB + s * 256 + ((128 + 32 * tf + 8 * lg) ^ ((s & 15) << 4))) = phkn[tf];
    }

    // ---- PV: out = w*(a@v) + phi@S  (A-frags are own-wave rows: no barrier)
    f32x4 oacc[4];
    #pragma unroll
    for (int td = 0; td < 4; ++td) oacc[td] = zero4();
    short8 aa0 = ldfrag(aAB, s, lg, 128, 7);
    short8 aa1 = ldfrag(aAB, s, 4 + lg, 128, 7);
    #pragma unroll
    for (int td = 0; td < 4; ++td) {
        oacc[td] = mfma(aa0, ldfrag(vT, td * 16 + lr, lg, 128, 7), oacc[td]);
        oacc[td] = mfma(aa1, ldfrag(vT, td * 16 + lr, 4 + lg, 128, 7), oacc[td]);
    }
    short8 pf[4];
    #pragma unroll
    for (int kc = 0; kc < 4; ++kc) pf[kc] = ldfrag(phiAB, s, kc * 4 + lg, 256, 15);
    #pragma unroll
    for (int td = 0; td < 4; ++td)
        #pragma unroll
        for (int kc = 0; kc < 4; ++kc)
            oacc[td] = mfma(pf[kc], ldfrag(St, td * 16 + lr, kc * 4 + lg, 256, 15), oacc[td]);

    // epilogue: broadcast inv from row-owner lane, store
    float* op = Out + base;
    #pragma unroll
    for (int r = 0; r < 4; ++r) {
        float invr = __shfl(inv, lg * 4 + r, 16);
        int sr = 16 * wv + lg * 4 + r;
        #pragma unroll
        for (int td = 0; td < 4; ++td)
            op[sr * 64 + td * 16 + lr] = oacc[td][r] * invr;
    }
}

// ---------------------------------------------------------------------------
extern "C" void kernel_launch(void* const* d_in, const int* in_sizes, int n_in,
                              void* d_out, int out_size, void* d_ws, size_t ws_size,
                              hipStream_t stream)
{
    const float* q     = (const float*)d_in[0];
    const float* k     = (const float*)d_in[1];
    const float* v     = (const float*)d_in[2];
    const float* W     = (const float*)d_in[3];
    const float* alpha = (const float*)d_in[4];
    float* out = (float*)d_out;

    ushort* wsSb = (ushort*)d_ws;                                        // 32 MB
    float*  wsZ  = (float*)((char*)d_ws + (size_t)NBLK * F2 * Dc * 2);   // 1 MB
    ushort* Wtb  = (ushort*)((char*)wsZ + (size_t)NBLK * F2 * 4);        // 128 KB

    passW<<<Hc, 256, 0, stream>>>(W, Wtb);
    passA<<<NBLK, 256, 0, stream>>>(k, v, Wtb, wsSb, wsZ);
    passB<<<288, 256, 0, stream>>>(wsSb, wsZ);
    passC<<<NBLK, 256, 0, stream>>>(q, k, v, Wtb, alpha, wsSb, wsZ, out);
}